// Round 4
// baseline (376.307 us; speedup 1.0000x reference)
//
#include <hip/hip_runtime.h>
#include <hip/hip_bf16.h>

// ---------------------------------------------------------------------------
// MSDeformableAttention on MI355X — round 3 (identical audited baseline)
//   k1: value = input_flatten @ W_v + b_v   (masked)      fp32 VALU GEMM
//   k2: off   = query @ W_off + b_off                     fp32 VALU GEMM
//   k3: attn  = query @ W_attn + b_attn  (raw logits)     fp32 VALU GEMM
//   k4: bilinear sampling + fused softmax + weighted acc -> pre[Lq,256]
//   k5: out = pre @ W_out + b_out                         fp32 VALU GEMM
// Shapes fixed by setup_inputs: Lq=L_in=21760, C=256, NH=8, NL=4, NP=4
// levels (128,128)(64,64)(32,32)(16,16), lsi {0,16384,20480,21504}
// ---------------------------------------------------------------------------

// ---- fp32 tiled GEMM: C[M,N] = A[M,K] @ B[K,N] + bias[N], optional row mask
// BM=64, BN=128, BK=32, 256 threads, 4x8 micro-tile per thread.
__global__ __launch_bounds__(256) void gemm_bias_f32(
    const float* __restrict__ A, const float* __restrict__ B,
    const float* __restrict__ bias, float* __restrict__ C,
    int M, int N, int K, const unsigned char* __restrict__ mask)
{
    constexpr int BM = 64, BN = 128, BK = 32;
    __shared__ float As[BK][BM + 4];   // transposed A tile; rows stay 16B-aligned
    __shared__ float Bs[BK][BN + 4];

    const int tid = threadIdx.x;
    const int m0 = blockIdx.y * BM;
    const int n0 = blockIdx.x * BN;
    const int tr = tid >> 4;          // 0..15 -> rows tr*4..tr*4+3
    const int tc = tid & 15;          // 0..15 -> cols tc*8..tc*8+7

    float acc[4][8] = {};

    for (int k0 = 0; k0 < K; k0 += BK) {
        // A tile 64x32 -> As[k][m] (transposed)
#pragma unroll
        for (int it = 0; it < (BM * BK) / 1024; ++it) {   // 2 float4 per thread
            int idx = tid + it * 256;
            int row = idx >> 3;        // 8 float4 per A row
            int c4  = idx & 7;
            const float4 av = *reinterpret_cast<const float4*>(
                A + (size_t)(m0 + row) * K + k0 + c4 * 4);
            As[c4 * 4 + 0][row] = av.x;
            As[c4 * 4 + 1][row] = av.y;
            As[c4 * 4 + 2][row] = av.z;
            As[c4 * 4 + 3][row] = av.w;
        }
        // B tile 32x128 -> Bs[k][n]
#pragma unroll
        for (int it = 0; it < (BK * BN) / 1024; ++it) {   // 4 float4 per thread
            int idx = tid + it * 256;
            int row = idx >> 5;        // 32 float4 per B row
            int c4  = idx & 31;
            *reinterpret_cast<float4*>(&Bs[row][c4 * 4]) =
                *reinterpret_cast<const float4*>(
                    B + (size_t)(k0 + row) * N + n0 + c4 * 4);
        }
        __syncthreads();

#pragma unroll
        for (int k = 0; k < BK; ++k) {
            const float4 a  = *reinterpret_cast<const float4*>(&As[k][tr * 4]);
            const float4 b0 = *reinterpret_cast<const float4*>(&Bs[k][tc * 8]);
            const float4 b1 = *reinterpret_cast<const float4*>(&Bs[k][tc * 8 + 4]);
            const float av[4] = {a.x, a.y, a.z, a.w};
            const float bv[8] = {b0.x, b0.y, b0.z, b0.w, b1.x, b1.y, b1.z, b1.w};
#pragma unroll
            for (int i = 0; i < 4; ++i)
#pragma unroll
                for (int j = 0; j < 8; ++j)
                    acc[i][j] = fmaf(av[i], bv[j], acc[i][j]);
        }
        __syncthreads();
    }

#pragma unroll
    for (int i = 0; i < 4; ++i) {
        const int m = m0 + tr * 4 + i;
        float mv = 1.f;
        if (mask) mv = mask[m] ? 0.f : 1.f;   // padding-mask zeroing (value GEMM)
#pragma unroll
        for (int j = 0; j < 8; j += 4) {
            const int n = n0 + tc * 8 + j;
            float4 o;
            o.x = (acc[i][j + 0] + bias[n + 0]) * mv;
            o.y = (acc[i][j + 1] + bias[n + 1]) * mv;
            o.z = (acc[i][j + 2] + bias[n + 2]) * mv;
            o.w = (acc[i][j + 3] + bias[n + 3]) * mv;
            *reinterpret_cast<float4*>(C + (size_t)m * N + n) = o;
        }
    }
}

// ---- bilinear sampling + fused 16-wide softmax + weighted accumulation
// grid = Lq blocks, 256 threads: thread = (h = tid>>5, c = tid&31)
// Each 32-lane channel group issues one coalesced 128B load per corner.
__global__ __launch_bounds__(256) void msda_sample_kernel(
    const float* __restrict__ value,   // [L_in, 8, 32]
    const float* __restrict__ off,     // [Lq, 256] raw offsets (bias included)
    const float* __restrict__ attn,    // [Lq, 128] raw logits
    const float* __restrict__ refp,    // [Lq, 4, 2]
    float* __restrict__ pre)           // [Lq, 256]
{
    __shared__ float s_off[256];
    __shared__ float s_attn[128];
    __shared__ float s_ref[8];

    const int q   = blockIdx.x;
    const int tid = threadIdx.x;
    s_off[tid] = off[(size_t)q * 256 + tid];
    if (tid < 128) s_attn[tid] = attn[(size_t)q * 128 + tid];
    if (tid < 8)   s_ref[tid]  = refp[(size_t)q * 8 + tid];
    __syncthreads();

    // softmax over each 16-chunk (one (q,h) group): lanes 0..127, width-16 shfl
    if (tid < 128) {
        float v = s_attn[tid];
        float m = v;
#pragma unroll
        for (int o = 1; o < 16; o <<= 1) m = fmaxf(m, __shfl_xor(m, o, 16));
        float e = expf(v - m);
        float s = e;
#pragma unroll
        for (int o = 1; o < 16; o <<= 1) s += __shfl_xor(s, o, 16);
        s_attn[tid] = e / s;
    }
    __syncthreads();

    const int h = tid >> 5, c = tid & 31;
    const int HW[4]  = {128, 64, 32, 16};
    const int LSI[4] = {0, 16384, 20480, 21504};

    float acc = 0.f;
#pragma unroll
    for (int l = 0; l < 4; ++l) {
        const int   Wi = HW[l], Hi = HW[l];
        const float Wf = (float)Wi, Hf = (float)Hi;
        const float rx = s_ref[l * 2 + 0], ry = s_ref[l * 2 + 1];
        const float* __restrict__ vbase = value + (size_t)LSI[l] * 256 + h * 32 + c;
#pragma unroll
        for (int p = 0; p < 4; ++p) {
            const float ox = s_off[h * 32 + l * 8 + p * 2 + 0];
            const float oy = s_off[h * 32 + l * 8 + p * 2 + 1];
            const float a  = s_attn[h * 16 + l * 4 + p];
            // matches reference: gx = rx + ox/W;  x = gx*W - 0.5
            const float x = (rx + ox / Wf) * Wf - 0.5f;
            const float y = (ry + oy / Hf) * Hf - 0.5f;
            const float x0f = floorf(x), y0f = floorf(y);
            const float dx = x - x0f, dy = y - y0f;
            const int x0 = (int)x0f, y0 = (int)y0f;
            const int x1 = x0 + 1,  y1 = y0 + 1;
            const float vx0 = (x0 >= 0 && x0 < Wi) ? 1.f : 0.f;
            const float vx1 = (x1 >= 0 && x1 < Wi) ? 1.f : 0.f;
            const float vy0 = (y0 >= 0 && y0 < Hi) ? 1.f : 0.f;
            const float vy1 = (y1 >= 0 && y1 < Hi) ? 1.f : 0.f;
            const int xc0 = min(max(x0, 0), Wi - 1), xc1 = min(max(x1, 0), Wi - 1);
            const int yc0 = min(max(y0, 0), Hi - 1), yc1 = min(max(y1, 0), Hi - 1);
            const float v00 = vbase[(yc0 * Wi + xc0) * 256];
            const float v01 = vbase[(yc0 * Wi + xc1) * 256];
            const float v10 = vbase[(yc1 * Wi + xc0) * 256];
            const float v11 = vbase[(yc1 * Wi + xc1) * 256];
            const float wx1 = dx, wx0 = 1.f - dx;
            const float wy1w = dy, wy0w = 1.f - dy;
            acc += a * (wy0w * (wx0 * vx0 * vy0 * v00 + wx1 * vx1 * vy0 * v01) +
                        wy1w * (wx0 * vx0 * vy1 * v10 + wx1 * vx1 * vy1 * v11));
        }
    }
    pre[(size_t)q * 256 + tid] = acc;
}

extern "C" void kernel_launch(void* const* d_in, const int* in_sizes, int n_in,
                              void* d_out, int out_size, void* d_ws, size_t ws_size,
                              hipStream_t stream)
{
    const float*         query  = (const float*)d_in[0];
    const float*         refp   = (const float*)d_in[1];
    const float*         inF    = (const float*)d_in[2];
    // d_in[3] spatial shapes / d_in[4] level start idx: fixed, hardcoded above
    const unsigned char* mask   = (const unsigned char*)d_in[5];
    const float*         W_off  = (const float*)d_in[6];
    const float*         b_off  = (const float*)d_in[7];
    const float*         W_attn = (const float*)d_in[8];
    const float*         b_attn = (const float*)d_in[9];
    const float*         W_v    = (const float*)d_in[10];
    const float*         b_v    = (const float*)d_in[11];
    const float*         W_out  = (const float*)d_in[12];
    const float*         b_out  = (const float*)d_in[13];
    float*               out    = (float*)d_out;

    const int M = in_sizes[0] / 256;        // Lq = L_in = 21760 (divisible by 64)
    const size_t SZ_VAL = (size_t)M * 256 * sizeof(float);
    const size_t SZ_ATT = (size_t)M * 128 * sizeof(float);

    // Workspace guard: refuse to run (clean correctness failure) rather than
    // write OOB and risk killing the container.
    if (ws_size < 3 * SZ_VAL + SZ_ATT) return;

    float* value = (float*)d_ws;                                   // [M,256]
    float* offb  = (float*)((char*)d_ws + SZ_VAL);                 // [M,256]
    float* attnb = (float*)((char*)d_ws + 2 * SZ_VAL);             // [M,128]
    float* pre   = (float*)((char*)d_ws + 2 * SZ_VAL + SZ_ATT);    // [M,256]

    const dim3 blk(256);
    gemm_bias_f32<<<dim3(2, M / 64), blk, 0, stream>>>(inF,   W_v,    b_v,    value, M, 256, 256, mask);
    gemm_bias_f32<<<dim3(2, M / 64), blk, 0, stream>>>(query, W_off,  b_off,  offb,  M, 256, 256, nullptr);
    gemm_bias_f32<<<dim3(1, M / 64), blk, 0, stream>>>(query, W_attn, b_attn, attnb, M, 128, 256, nullptr);
    msda_sample_kernel<<<dim3(M), blk, 0, stream>>>(value, offb, attnb, refp, pre);
    gemm_bias_f32<<<dim3(2, M / 64), blk, 0, stream>>>(pre, W_out, b_out, out, M, 256, 256, nullptr);
}

// Round 5
// 276.535 us; speedup vs baseline: 1.3608x; 1.3608x over previous
//
#include <hip/hip_runtime.h>
#include <hip/hip_bf16.h>
#include <hip/hip_fp16.h>

// ---------------------------------------------------------------------------
// MSDeformableAttention on MI355X — round 4: split-f16 MFMA GEMMs + lean sampler
//
// C = A@W via fp16 hi/lo split: hi*hi + lo*hi + hi*lo  (err ~2^-24, MFMA rate)
//   A'' [M,512] f16 = [hi(A) | lo(A)]; K-loop steps 8..11 re-read the hi block.
//   B'' [N,768] f16 (transposed, k-contiguous) = [Bhi ; Bhi ; Blo] k-blocks.
// Pipeline:
//   convA(inF)->A1; gemm(A1,Btv)->valueH(f16,masked)
//   convA(query)->A1; gemm(A1,Btoa,N=384)->offattn(f32)
//   sample(valueH,offattn,ref) -> preA(A1, already hi|lo split)
//   gemm(A1,Btout)->out
// Shapes fixed: M=Lq=L_in=21760, C=256, NH=8, NL=4, NP=4,
// levels (128,128)(64,64)(32,32)(16,16), lsi {0,16384,20480,21504}
// ---------------------------------------------------------------------------

typedef _Float16 f16;
typedef _Float16 f16x8 __attribute__((ext_vector_type(8)));
typedef _Float16 f16x4 __attribute__((ext_vector_type(4)));
typedef float    f32x4 __attribute__((ext_vector_type(4)));

__device__ __forceinline__ void g2lds16(const void* gp, void* lp) {
    __builtin_amdgcn_global_load_lds(
        (const __attribute__((address_space(1))) unsigned int*)gp,
        (__attribute__((address_space(3))) unsigned int*)lp, 16, 0, 0);
}

// ---- split-f16 MFMA GEMM: C[M,N] = A''[M,512] x B''[N,768]^T + bias
// 128x128 tile, 256 thr (4 waves 2x2), BK=64, 16x16x32_f16, XOR-swizzled LDS.
template <bool HALF_OUT, bool MASKED>
__global__ __launch_bounds__(256) void gemm_split_f16(
    const f16* __restrict__ A,   // [M,512] row-major (hi | lo)
    const f16* __restrict__ Bt,  // [N,768] row-major (k contiguous per n)
    const float* __restrict__ bias,  // [N]
    void* __restrict__ Cout, int M, int N,
    const unsigned char* __restrict__ mask)
{
    __shared__ __align__(16) f16 As[128 * 64];
    __shared__ __align__(16) f16 Bs[128 * 64];

    const int tid  = threadIdx.x;
    const int m0   = blockIdx.y * 128, n0 = blockIdx.x * 128;
    const int lane = tid & 63, wid = tid >> 6;
    const int wm   = (wid >> 1) * 64, wn = (wid & 1) * 64;

    f32x4 acc[4][4] = {};

    // staging: pass p, thread t -> LDS byte p*4096 + t*16  (linear in lane, rule #21)
    // row r = p*32 + (t>>3), dest chunk = t&7; source chunk = (t&7) ^ (r&7)
    const int sr  = tid >> 3;
    const int sch = tid & 7;

    for (int kt = 0; kt < 12; ++kt) {
        const int kA = (kt < 8 ? kt : kt - 8) * 64;   // revisit hi block for hi*Blo
        const int kB = kt * 64;
#pragma unroll
        for (int p = 0; p < 4; ++p) {
            const int r = p * 32 + sr;
            const int gc = (sch ^ (r & 7)) << 3;      // f16 col within 64-wide tile
            g2lds16(A + (size_t)(m0 + r) * 512 + kA + gc, &As[r * 64 + sch * 8]);
        }
#pragma unroll
        for (int p = 0; p < 4; ++p) {
            const int r = p * 32 + sr;
            const int gc = (sch ^ (r & 7)) << 3;
            g2lds16(Bt + (size_t)(n0 + r) * 768 + kB + gc, &Bs[r * 64 + sch * 8]);
        }
        __syncthreads();

#pragma unroll
        for (int kf = 0; kf < 2; ++kf) {
            const int kch = kf * 4 + (lane >> 4);     // k chunk 0..7
            f16x8 av[4], bv[4];
#pragma unroll
            for (int mf = 0; mf < 4; ++mf) {
                const int row = wm + mf * 16 + (lane & 15);
                av[mf] = *(const f16x8*)&As[row * 64 + ((kch ^ (row & 7)) << 3)];
            }
#pragma unroll
            for (int nf = 0; nf < 4; ++nf) {
                const int row = wn + nf * 16 + (lane & 15);
                bv[nf] = *(const f16x8*)&Bs[row * 64 + ((kch ^ (row & 7)) << 3)];
            }
#pragma unroll
            for (int mf = 0; mf < 4; ++mf)
#pragma unroll
                for (int nf = 0; nf < 4; ++nf)
                    acc[mf][nf] = __builtin_amdgcn_mfma_f32_16x16x32_f16(
                        av[mf], bv[nf], acc[mf][nf], 0, 0, 0);
        }
        __syncthreads();
    }

    // epilogue — C/D layout: col = lane&15, row = (lane>>4)*4 + reg  [m89-verified]
#pragma unroll
    for (int mf = 0; mf < 4; ++mf) {
        const int rb = m0 + wm + mf * 16 + ((lane >> 4) << 2);
#pragma unroll
        for (int nf = 0; nf < 4; ++nf) {
            const int col = n0 + wn + nf * 16 + (lane & 15);
            const float bc = bias[col];
#pragma unroll
            for (int j = 0; j < 4; ++j) {
                const int row = rb + j;
                float v = acc[mf][nf][j] + bc;
                if (MASKED) v = mask[row] ? 0.f : v;
                if (HALF_OUT)
                    ((__half*)Cout)[(size_t)row * N + col] = __float2half(v);
                else
                    ((float*)Cout)[(size_t)row * N + col] = v;
            }
        }
    }
}

// ---- A-convert: [M,256] f32 -> [M,512] f16 (hi | lo)
__global__ __launch_bounds__(256) void convA_kernel(
    const float* __restrict__ in, f16* __restrict__ out, int total4)
{
    const int i = blockIdx.x * 256 + threadIdx.x;
    if (i >= total4) return;
    const int m = i >> 6, k4 = (i & 63) << 2;
    const float4 v = reinterpret_cast<const float4*>(in)[i];
    f16x4 hi, lo;
    hi.x = (f16)v.x; lo.x = (f16)(v.x - (float)hi.x);
    hi.y = (f16)v.y; lo.y = (f16)(v.y - (float)hi.y);
    hi.z = (f16)v.z; lo.z = (f16)(v.z - (float)hi.z);
    hi.w = (f16)v.w; lo.w = (f16)(v.w - (float)hi.w);
    *reinterpret_cast<f16x4*>(&out[(size_t)m * 512 + k4])       = hi;
    *reinterpret_cast<f16x4*>(&out[(size_t)m * 512 + 256 + k4]) = lo;
}

// ---- B-convert: W [256, ncols] f32 -> Bt [ncols, 768] f16 = [hi; hi; lo]
__global__ __launch_bounds__(256) void convB_kernel(
    const float* __restrict__ W, int ncols, f16* __restrict__ Bt)
{
    const int i = blockIdx.x * 256 + threadIdx.x;
    if (i >= ncols * 768) return;
    const int n = i / 768, k = i - n * 768;
    const int ks = k & 255;
    const float w = W[(size_t)ks * ncols + n];
    const f16 h = (f16)w;
    Bt[(size_t)n * 768 + k] = (k < 512) ? h : (f16)(w - (float)h);
}

// ---- bias concat: [b_off(256) | b_attn(128)]
__global__ void biascat_kernel(const float* __restrict__ b0,
                               const float* __restrict__ b1,
                               float* __restrict__ out)
{
    const int i = threadIdx.x;  // 384 threads
    out[i] = (i < 256) ? b0[i] : b1[i - 256];
}

// ---- sampling: phase-1 per-(h,point) softmax+coords+weights in LDS,
//      phase-2 gather f16 value + FMA; writes pre directly as (hi|lo) split.
__global__ __launch_bounds__(256) void msda_sample_f16(
    const __half* __restrict__ value,    // [L,256] f16
    const float* __restrict__ offattn,   // [M,384]: off(256) | attn logits(128)
    const float* __restrict__ refp,      // [M,4,2]
    f16* __restrict__ preA)              // [M,512] (hi | lo)
{
    __shared__ float s_off[256];
    __shared__ float s_logit[128];
    __shared__ float s_ref[8];
    __shared__ __align__(16) float s_w[512];
    __shared__ __align__(16) int   s_i[512];

    const int q = blockIdx.x, tid = threadIdx.x;
    s_off[tid] = offattn[(size_t)q * 384 + tid];
    if (tid < 128) s_logit[tid] = offattn[(size_t)q * 384 + 256 + tid];
    if (tid < 8)   s_ref[tid]   = refp[(size_t)q * 8 + tid];
    __syncthreads();

    if (tid < 128) {
        const int h = tid >> 4, pp = tid & 15, l = pp >> 2, p = pp & 3;
        // softmax over the 16 logits of head h (16-lane aligned groups)
        float v = s_logit[tid];
        float mx = v;
#pragma unroll
        for (int o = 1; o < 16; o <<= 1) mx = fmaxf(mx, __shfl_xor(mx, o, 16));
        float e = expf(v - mx);
        float s = e;
#pragma unroll
        for (int o = 1; o < 16; o <<= 1) s += __shfl_xor(s, o, 16);
        const float a = e / s;

        const int HW_[4]  = {128, 64, 32, 16};
        const int LSI_[4] = {0, 16384, 20480, 21504};
        const int   Wi = HW_[l], Hi = Wi;
        const float Wf = (float)Wi, Hf = Wf;
        const float rx = s_ref[l * 2 + 0], ry = s_ref[l * 2 + 1];
        const float ox = s_off[h * 32 + l * 8 + p * 2 + 0];
        const float oy = s_off[h * 32 + l * 8 + p * 2 + 1];
        const float x = (rx + ox / Wf) * Wf - 0.5f;
        const float y = (ry + oy / Hf) * Hf - 0.5f;
        const float x0f = floorf(x), y0f = floorf(y);
        const float dx = x - x0f, dy = y - y0f;
        const int x0 = (int)x0f, y0 = (int)y0f;
        const int x1 = x0 + 1, y1 = y0 + 1;
        const float vx0 = (x0 >= 0 && x0 < Wi) ? 1.f : 0.f;
        const float vx1 = (x1 >= 0 && x1 < Wi) ? 1.f : 0.f;
        const float vy0 = (y0 >= 0 && y0 < Hi) ? 1.f : 0.f;
        const float vy1 = (y1 >= 0 && y1 < Hi) ? 1.f : 0.f;
        const int xc0 = min(max(x0, 0), Wi - 1), xc1 = min(max(x1, 0), Wi - 1);
        const int yc0 = min(max(y0, 0), Hi - 1), yc1 = min(max(y1, 0), Hi - 1);
        const int base = LSI_[l];
        const int b4 = tid * 4;
        s_i[b4 + 0] = (base + yc0 * Wi + xc0) * 256;
        s_i[b4 + 1] = (base + yc0 * Wi + xc1) * 256;
        s_i[b4 + 2] = (base + yc1 * Wi + xc0) * 256;
        s_i[b4 + 3] = (base + yc1 * Wi + xc1) * 256;
        s_w[b4 + 0] = a * (1.f - dy) * (1.f - dx) * vy0 * vx0;
        s_w[b4 + 1] = a * (1.f - dy) * dx        * vy0 * vx1;
        s_w[b4 + 2] = a * dy        * (1.f - dx) * vy1 * vx0;
        s_w[b4 + 3] = a * dy        * dx        * vy1 * vx1;
    }
    __syncthreads();

    const int h = tid >> 5, c = tid & 31;
    const __half* __restrict__ vb = value + h * 32 + c;
    float acc = 0.f;
#pragma unroll
    for (int pp = 0; pp < 16; ++pp) {
        const int b = (h * 16 + pp) * 4;
        const int4   idx = *reinterpret_cast<const int4*>(&s_i[b]);
        const float4 w   = *reinterpret_cast<const float4*>(&s_w[b]);
        acc += w.x * __half2float(vb[idx.x]);
        acc += w.y * __half2float(vb[idx.y]);
        acc += w.z * __half2float(vb[idx.z]);
        acc += w.w * __half2float(vb[idx.w]);
    }
    const f16 hi = (f16)acc;
    preA[(size_t)q * 512 + tid]       = hi;
    preA[(size_t)q * 512 + 256 + tid] = (f16)(acc - (float)hi);
}

extern "C" void kernel_launch(void* const* d_in, const int* in_sizes, int n_in,
                              void* d_out, int out_size, void* d_ws, size_t ws_size,
                              hipStream_t stream)
{
    const float*         query  = (const float*)d_in[0];
    const float*         refp   = (const float*)d_in[1];
    const float*         inF    = (const float*)d_in[2];
    const unsigned char* mask   = (const unsigned char*)d_in[5];
    const float*         W_off  = (const float*)d_in[6];
    // d_in[7] b_off
    const float*         W_attn = (const float*)d_in[8];
    const float*         b_attn = (const float*)d_in[9];
    const float*         W_v    = (const float*)d_in[10];
    const float*         b_v    = (const float*)d_in[11];
    const float*         W_out  = (const float*)d_in[12];
    const float*         b_out  = (const float*)d_in[13];
    const float*         b_off  = (const float*)d_in[7];
    float*               out    = (float*)d_out;

    const int M = in_sizes[0] / 256;          // 21760
    if (M % 128 != 0) return;                 // tiling assumption guard

    // workspace layout (all 256B-aligned)
    const size_t SZ_A1  = (size_t)M * 512 * sizeof(f16);      // 22.3 MB
    const size_t SZ_VAL = (size_t)M * 256 * sizeof(__half);   // 11.1 MB
    const size_t SZ_OA  = (size_t)M * 384 * sizeof(float);    // 33.4 MB
    const size_t SZ_BTV = 256 * 768 * sizeof(f16);
    const size_t SZ_BTO = 384 * 768 * sizeof(f16);
    char* w = (char*)d_ws;
    f16*    A1     = (f16*)w;                      w += SZ_A1;
    __half* valueH = (__half*)w;                   w += SZ_VAL;
    float*  offattn= (float*)w;                    w += SZ_OA;
    f16*    Btv    = (f16*)w;                      w += SZ_BTV;
    f16*    Btoa   = (f16*)w;                      w += SZ_BTO;
    f16*    Btout  = (f16*)w;                      w += SZ_BTV;
    float*  boa    = (float*)w;                    w += 512 * sizeof(float);
    if ((size_t)(w - (char*)d_ws) > ws_size) return;  // clean fail, no OOB

    const dim3 blk(256);
    const int convA_blocks = (M * 64 + 255) / 256;

    // weight preprocessing (tiny)
    convB_kernel<<<dim3((256 * 768 + 255) / 256), blk, 0, stream>>>(W_v,   256, Btv);
    convB_kernel<<<dim3((256 * 768 + 255) / 256), blk, 0, stream>>>(W_off, 256, Btoa);
    convB_kernel<<<dim3((128 * 768 + 255) / 256), blk, 0, stream>>>(W_attn,128, Btoa + (size_t)256 * 768);
    convB_kernel<<<dim3((256 * 768 + 255) / 256), blk, 0, stream>>>(W_out, 256, Btout);
    biascat_kernel<<<dim3(1), dim3(384), 0, stream>>>(b_off, b_attn, boa);

    // value = inF @ W_v + b_v (masked) -> f16
    convA_kernel<<<dim3(convA_blocks), blk, 0, stream>>>(inF, A1, M * 64);
    gemm_split_f16<true, true><<<dim3(2, M / 128), blk, 0, stream>>>(
        A1, Btv, b_v, valueH, M, 256, mask);

    // [off | attn logits] = query @ [W_off|W_attn] + [b_off|b_attn]
    convA_kernel<<<dim3(convA_blocks), blk, 0, stream>>>(query, A1, M * 64);
    gemm_split_f16<false, false><<<dim3(3, M / 128), blk, 0, stream>>>(
        A1, Btoa, boa, offattn, M, 384, nullptr);

    // sampling (+softmax) -> preA (hi|lo) into A1 (query-A dead now)
    msda_sample_f16<<<dim3(M), blk, 0, stream>>>(valueH, offattn, refp, A1);

    // out = pre @ W_out + b_out
    gemm_split_f16<false, false><<<dim3(2, M / 128), blk, 0, stream>>>(
        A1, Btout, b_out, out, M, 256, nullptr);
}

// Round 6
// 229.170 us; speedup vs baseline: 1.6420x; 1.2067x over previous
//
#include <hip/hip_runtime.h>
#include <hip/hip_bf16.h>
#include <hip/hip_fp16.h>

// ---------------------------------------------------------------------------
// MSDeformableAttention on MI355X — round 5
//  - split-f16 MFMA GEMM retiled 64x128 / 512 thr (8 waves) for occupancy
//  - sampler v2: 2 queries/block, half2 gathers, fma_mix idiom
//  - one fused weight-prep kernel
// Split trick: C = Ahi*Bhi + Alo*Bhi + Ahi*Blo (fp16 pairs, fp32 MFMA acc)
//   A'' [M,512] f16 = [hi | lo];  B'' [N,768] f16 = [Bhi ; Bhi ; Blo]
// Shapes fixed: M=Lq=L_in=21760, C=256, NH=8, NL=4, NP=4,
// levels (128,128)(64,64)(32,32)(16,16), lsi {0,16384,20480,21504}
// ---------------------------------------------------------------------------

typedef _Float16 f16;
typedef _Float16 f16x8 __attribute__((ext_vector_type(8)));
typedef _Float16 f16x4 __attribute__((ext_vector_type(4)));
typedef _Float16 f16x2 __attribute__((ext_vector_type(2)));
typedef float    f32x4 __attribute__((ext_vector_type(4)));

__device__ __forceinline__ void g2lds16(const void* gp, void* lp) {
    __builtin_amdgcn_global_load_lds(
        (const __attribute__((address_space(1))) unsigned int*)gp,
        (__attribute__((address_space(3))) unsigned int*)lp, 16, 0, 0);
}

// ---- split-f16 MFMA GEMM: C[M,N] = A''[M,512] x B''[N,768]^T + bias
// 64x128 tile, 512 thr (8 waves 2x4, wave-tile 32x32), BK=64, XOR-swizzled LDS.
template <bool HALF_OUT, bool MASKED>
__global__ __launch_bounds__(512) void gemm_split_f16(
    const f16* __restrict__ A,   // [M,512] row-major (hi | lo)
    const f16* __restrict__ Bt,  // [N,768] row-major (k contiguous per n)
    const float* __restrict__ bias,  // [N]
    void* __restrict__ Cout, int M, int N,
    const unsigned char* __restrict__ mask)
{
    __shared__ __align__(16) f16 As[64 * 64];    // 8 KB
    __shared__ __align__(16) f16 Bs[128 * 64];   // 16 KB

    const int tid  = threadIdx.x;
    const int m0   = blockIdx.y * 64, n0 = blockIdx.x * 128;
    const int lane = tid & 63, wid = tid >> 6;
    const int wm   = (wid >> 2) * 32, wn = (wid & 3) * 32;

    f32x4 acc[2][2] = {};

    // staging: thread t -> LDS 16B chunk at row r=(t>>3)[+64p], chunk t&7
    // (linear in lane => valid global_load_lds dest; source pre-swizzled)
    const int sr  = tid >> 3;      // 0..63
    const int sch = tid & 7;

    for (int kt = 0; kt < 12; ++kt) {
        const int kA = (kt < 8 ? kt : kt - 8) * 64;   // revisit hi block: Ahi*Blo
        const int kB = kt * 64;
        {   // A tile 64x64: one pass
            const int r = sr;
            const int gc = (sch ^ (r & 7)) << 3;
            g2lds16(A + (size_t)(m0 + r) * 512 + kA + gc, &As[r * 64 + sch * 8]);
        }
#pragma unroll
        for (int p = 0; p < 2; ++p) {   // B tile 128x64: two passes
            const int r = p * 64 + sr;
            const int gc = (sch ^ (r & 7)) << 3;
            g2lds16(Bt + (size_t)(n0 + r) * 768 + kB + gc, &Bs[r * 64 + sch * 8]);
        }
        __syncthreads();

#pragma unroll
        for (int kf = 0; kf < 2; ++kf) {
            const int kch = kf * 4 + (lane >> 4);     // k chunk 0..7
            f16x8 av[2], bv[2];
#pragma unroll
            for (int mf = 0; mf < 2; ++mf) {
                const int row = wm + mf * 16 + (lane & 15);
                av[mf] = *(const f16x8*)&As[row * 64 + ((kch ^ (row & 7)) << 3)];
            }
#pragma unroll
            for (int nf = 0; nf < 2; ++nf) {
                const int row = wn + nf * 16 + (lane & 15);
                bv[nf] = *(const f16x8*)&Bs[row * 64 + ((kch ^ (row & 7)) << 3)];
            }
#pragma unroll
            for (int mf = 0; mf < 2; ++mf)
#pragma unroll
                for (int nf = 0; nf < 2; ++nf)
                    acc[mf][nf] = __builtin_amdgcn_mfma_f32_16x16x32_f16(
                        av[mf], bv[nf], acc[mf][nf], 0, 0, 0);
        }
        __syncthreads();
    }

    // epilogue — C/D layout: col = lane&15, row = (lane>>4)*4 + reg  [m89]
#pragma unroll
    for (int mf = 0; mf < 2; ++mf) {
        const int rb = m0 + wm + mf * 16 + ((lane >> 4) << 2);
#pragma unroll
        for (int nf = 0; nf < 2; ++nf) {
            const int col = n0 + wn + nf * 16 + (lane & 15);
            const float bc = bias[col];
#pragma unroll
            for (int j = 0; j < 4; ++j) {
                const int row = rb + j;
                float v = acc[mf][nf][j] + bc;
                if (MASKED) v = mask[row] ? 0.f : v;
                if (HALF_OUT)
                    ((__half*)Cout)[(size_t)row * N + col] = __float2half(v);
                else
                    ((float*)Cout)[(size_t)row * N + col] = v;
            }
        }
    }
}

// ---- A-convert: [M,256] f32 -> [M,512] f16 (hi | lo)
__global__ __launch_bounds__(256) void convA_kernel(
    const float* __restrict__ in, f16* __restrict__ out, int total4)
{
    const int i = blockIdx.x * 256 + threadIdx.x;
    if (i >= total4) return;
    const int m = i >> 6, k4 = (i & 63) << 2;
    const float4 v = reinterpret_cast<const float4*>(in)[i];
    f16x4 hi, lo;
    hi.x = (f16)v.x; lo.x = (f16)(v.x - (float)hi.x);
    hi.y = (f16)v.y; lo.y = (f16)(v.y - (float)hi.y);
    hi.z = (f16)v.z; lo.z = (f16)(v.z - (float)hi.z);
    hi.w = (f16)v.w; lo.w = (f16)(v.w - (float)hi.w);
    *reinterpret_cast<f16x4*>(&out[(size_t)m * 512 + k4])       = hi;
    *reinterpret_cast<f16x4*>(&out[(size_t)m * 512 + 256 + k4]) = lo;
}

// ---- fused weight prep: Btv | Btoa(off+attn) | Btout | boa
// Bt row n holds [hi(W[:,n]) ; hi(W[:,n]) ; lo(W[:,n])] (k contiguous)
__global__ __launch_bounds__(256) void prep_kernel(
    const float* __restrict__ Wv,   const float* __restrict__ Woff,
    const float* __restrict__ Wattn,const float* __restrict__ Wout,
    const float* __restrict__ boff, const float* __restrict__ battn,
    f16* __restrict__ Btv, f16* __restrict__ Btoa, f16* __restrict__ Btout,
    float* __restrict__ boa)
{
    const int i = blockIdx.x * 256 + threadIdx.x;
    constexpr int S0 = 256 * 768, S1 = 256 * 768, S2 = 128 * 768, S3 = 256 * 768;
    if (i < S0) {                                // W_v -> Btv
        const int n = i / 768, k = i - n * 768, ks = k & 255;
        const float w = Wv[(size_t)ks * 256 + n];
        const f16 h = (f16)w;
        Btv[i] = (k < 512) ? h : (f16)(w - (float)h);
    } else if (i < S0 + S1) {                    // W_off -> Btoa rows 0..255
        const int j = i - S0;
        const int n = j / 768, k = j - n * 768, ks = k & 255;
        const float w = Woff[(size_t)ks * 256 + n];
        const f16 h = (f16)w;
        Btoa[j] = (k < 512) ? h : (f16)(w - (float)h);
    } else if (i < S0 + S1 + S2) {               // W_attn -> Btoa rows 256..383
        const int j = i - S0 - S1;
        const int n = j / 768, k = j - n * 768, ks = k & 255;
        const float w = Wattn[(size_t)ks * 128 + n];
        const f16 h = (f16)w;
        Btoa[(size_t)(256 + n) * 768 + k] = (k < 512) ? h : (f16)(w - (float)h);
    } else if (i < S0 + S1 + S2 + S3) {          // W_out -> Btout
        const int j = i - S0 - S1 - S2;
        const int n = j / 768, k = j - n * 768, ks = k & 255;
        const float w = Wout[(size_t)ks * 256 + n];
        const f16 h = (f16)w;
        Btout[j] = (k < 512) ? h : (f16)(w - (float)h);
    } else if (i < S0 + S1 + S2 + S3 + 384) {    // bias concat
        const int j = i - S0 - S1 - S2 - S3;
        boa[j] = (j < 256) ? boff[j] : battn[j - 256];
    }
}

// ---- sampler v2: 2 queries/block; thread=(q,h,half2-pair); half2 gathers
__global__ __launch_bounds__(256) void msda_sample_v2(
    const __half* __restrict__ value,    // [L,256] f16
    const float* __restrict__ offattn,   // [M,384]: off(256) | attn logits(128)
    const float* __restrict__ refp,      // [M,4,2]
    f16* __restrict__ preA)              // [M,512] (hi | lo)
{
    __shared__ float s_off[2][256];
    __shared__ float s_ref[2][8];
    __shared__ __align__(16) float s_w[2][512];
    __shared__ __align__(16) int   s_i[2][512];

    const int q0 = blockIdx.x * 2, tid = threadIdx.x;
#pragma unroll
    for (int j = 0; j < 2; ++j) {
        const int idx = tid + j * 256;          // 0..511
        const int ql = idx >> 8, col = idx & 255;
        s_off[ql][col] = offattn[(size_t)(q0 + ql) * 384 + col];
    }
    if (tid < 16) s_ref[tid >> 3][tid & 7] = refp[(size_t)(q0 + (tid >> 3)) * 8 + (tid & 7)];
    __syncthreads();

    // phase 1: all 256 threads -> (query, head, point); softmax + coords + weights
    {
        const int ql = tid >> 7, slot = tid & 127;
        const int h = slot >> 4, pp = slot & 15, l = pp >> 2, p = pp & 3;
        float v = offattn[(size_t)(q0 + ql) * 384 + 256 + slot];   // logit
        float mx = v;
#pragma unroll
        for (int o = 1; o < 16; o <<= 1) mx = fmaxf(mx, __shfl_xor(mx, o, 16));
        const float e = expf(v - mx);
        float s = e;
#pragma unroll
        for (int o = 1; o < 16; o <<= 1) s += __shfl_xor(s, o, 16);
        const float a = e / s;

        const int HW_[4]  = {128, 64, 32, 16};
        const int LSI_[4] = {0, 16384, 20480, 21504};
        const int   Wi = HW_[l];
        const float Wf = (float)Wi;
        const float rx = s_ref[ql][l * 2 + 0], ry = s_ref[ql][l * 2 + 1];
        const float ox = s_off[ql][h * 32 + l * 8 + p * 2 + 0];
        const float oy = s_off[ql][h * 32 + l * 8 + p * 2 + 1];
        const float x = (rx + ox / Wf) * Wf - 0.5f;
        const float y = (ry + oy / Wf) * Wf - 0.5f;
        const float x0f = floorf(x), y0f = floorf(y);
        const float dx = x - x0f, dy = y - y0f;
        const int x0 = (int)x0f, y0 = (int)y0f;
        const int x1 = x0 + 1, y1 = y0 + 1;
        const float vx0 = (x0 >= 0 && x0 < Wi) ? 1.f : 0.f;
        const float vx1 = (x1 >= 0 && x1 < Wi) ? 1.f : 0.f;
        const float vy0 = (y0 >= 0 && y0 < Wi) ? 1.f : 0.f;
        const float vy1 = (y1 >= 0 && y1 < Wi) ? 1.f : 0.f;
        const int xc0 = min(max(x0, 0), Wi - 1), xc1 = min(max(x1, 0), Wi - 1);
        const int yc0 = min(max(y0, 0), Wi - 1), yc1 = min(max(y1, 0), Wi - 1);
        const int base = LSI_[l];
        const int b4 = slot * 4;
        s_i[ql][b4 + 0] = (base + yc0 * Wi + xc0) * 256;
        s_i[ql][b4 + 1] = (base + yc0 * Wi + xc1) * 256;
        s_i[ql][b4 + 2] = (base + yc1 * Wi + xc0) * 256;
        s_i[ql][b4 + 3] = (base + yc1 * Wi + xc1) * 256;
        s_w[ql][b4 + 0] = a * (1.f - dy) * (1.f - dx) * vy0 * vx0;
        s_w[ql][b4 + 1] = a * (1.f - dy) * dx         * vy0 * vx1;
        s_w[ql][b4 + 2] = a * dy         * (1.f - dx) * vy1 * vx0;
        s_w[ql][b4 + 3] = a * dy         * dx         * vy1 * vx1;
    }
    __syncthreads();

    // phase 2: thread=(ql, h, cp): gather half2, fma_mix accumulate
    const int ql = tid >> 7, slot = tid & 127;
    const int h = slot >> 4, cp = slot & 15;
    const __half* __restrict__ vb = value + h * 32 + cp * 2;
    float acc0 = 0.f, acc1 = 0.f;
#pragma unroll
    for (int pp = 0; pp < 16; ++pp) {
        const int b = (h * 16 + pp) * 4;
        const int4   idx = *reinterpret_cast<const int4*>(&s_i[ql][b]);
        const float4 w   = *reinterpret_cast<const float4*>(&s_w[ql][b]);
        const __half2 v0 = *reinterpret_cast<const __half2*>(vb + idx.x);
        const __half2 v1 = *reinterpret_cast<const __half2*>(vb + idx.y);
        const __half2 v2 = *reinterpret_cast<const __half2*>(vb + idx.z);
        const __half2 v3 = *reinterpret_cast<const __half2*>(vb + idx.w);
        acc0 = fmaf(w.x, __half2float(v0.x), acc0);
        acc1 = fmaf(w.x, __half2float(v0.y), acc1);
        acc0 = fmaf(w.y, __half2float(v1.x), acc0);
        acc1 = fmaf(w.y, __half2float(v1.y), acc1);
        acc0 = fmaf(w.z, __half2float(v2.x), acc0);
        acc1 = fmaf(w.z, __half2float(v2.y), acc1);
        acc0 = fmaf(w.w, __half2float(v3.x), acc0);
        acc1 = fmaf(w.w, __half2float(v3.y), acc1);
    }
    const int q = q0 + ql;
    const f16 h0 = (f16)acc0, h1 = (f16)acc1;
    const f16 l0 = (f16)(acc0 - (float)h0), l1 = (f16)(acc1 - (float)h1);
    f16x2 hv; hv.x = h0; hv.y = h1;
    f16x2 lv; lv.x = l0; lv.y = l1;
    *reinterpret_cast<f16x2*>(&preA[(size_t)q * 512 + h * 32 + cp * 2])       = hv;
    *reinterpret_cast<f16x2*>(&preA[(size_t)q * 512 + 256 + h * 32 + cp * 2]) = lv;
}

extern "C" void kernel_launch(void* const* d_in, const int* in_sizes, int n_in,
                              void* d_out, int out_size, void* d_ws, size_t ws_size,
                              hipStream_t stream)
{
    const float*         query  = (const float*)d_in[0];
    const float*         refp   = (const float*)d_in[1];
    const float*         inF    = (const float*)d_in[2];
    const unsigned char* mask   = (const unsigned char*)d_in[5];
    const float*         W_off  = (const float*)d_in[6];
    const float*         b_off  = (const float*)d_in[7];
    const float*         W_attn = (const float*)d_in[8];
    const float*         b_attn = (const float*)d_in[9];
    const float*         W_v    = (const float*)d_in[10];
    const float*         b_v    = (const float*)d_in[11];
    const float*         W_out  = (const float*)d_in[12];
    const float*         b_out  = (const float*)d_in[13];
    float*               out    = (float*)d_out;

    const int M = in_sizes[0] / 256;          // 21760
    if (M % 128 != 0) return;                 // tiling/pairing guard

    const size_t SZ_A1  = (size_t)M * 512 * sizeof(f16);      // 22.3 MB
    const size_t SZ_VAL = (size_t)M * 256 * sizeof(__half);   // 11.1 MB
    const size_t SZ_OA  = (size_t)M * 384 * sizeof(float);    // 33.4 MB
    const size_t SZ_BTV = 256 * 768 * sizeof(f16);
    const size_t SZ_BTO = 384 * 768 * sizeof(f16);
    char* w = (char*)d_ws;
    f16*    A1     = (f16*)w;                      w += SZ_A1;
    __half* valueH = (__half*)w;                   w += SZ_VAL;
    float*  offattn= (float*)w;                    w += SZ_OA;
    f16*    Btv    = (f16*)w;                      w += SZ_BTV;
    f16*    Btoa   = (f16*)w;                      w += SZ_BTO;
    f16*    Btout  = (f16*)w;                      w += SZ_BTV;
    float*  boa    = (float*)w;                    w += 512 * sizeof(float);
    if ((size_t)(w - (char*)d_ws) > ws_size) return;  // clean fail, no OOB

    const dim3 blk256(256), blk512(512);
    const int convA_blocks = (M * 64 + 255) / 256;
    const int prep_total = 3 * 256 * 768 + 128 * 768 + 384;

    prep_kernel<<<dim3((prep_total + 255) / 256), blk256, 0, stream>>>(
        W_v, W_off, W_attn, W_out, b_off, b_attn, Btv, Btoa, Btout, boa);

    // value = inF @ W_v + b_v (masked) -> f16
    convA_kernel<<<dim3(convA_blocks), blk256, 0, stream>>>(inF, A1, M * 64);
    gemm_split_f16<true, true><<<dim3(2, M / 64), blk512, 0, stream>>>(
        A1, Btv, b_v, valueH, M, 256, mask);

    // [off | attn logits] = query @ [W_off|W_attn] + [b_off|b_attn]
    convA_kernel<<<dim3(convA_blocks), blk256, 0, stream>>>(query, A1, M * 64);
    gemm_split_f16<false, false><<<dim3(3, M / 64), blk512, 0, stream>>>(
        A1, Btoa, boa, offattn, M, 384, nullptr);

    // sampling (+softmax) -> preA (hi|lo) into A1
    msda_sample_v2<<<dim3(M / 2), blk256, 0, stream>>>(valueH, offattn, refp, A1);

    // out = pre @ W_out + b_out
    gemm_split_f16<false, false><<<dim3(2, M / 64), blk512, 0, stream>>>(
        A1, Btout, b_out, out, M, 256, nullptr);
}

// Round 7
// 225.598 us; speedup vs baseline: 1.6680x; 1.0158x over previous
//
#include <hip/hip_runtime.h>
#include <hip/hip_bf16.h>
#include <hip/hip_fp16.h>

// ---------------------------------------------------------------------------
// MSDeformableAttention on MI355X — round 6
//  - gemm_f32a: reads A in f32, converts hi/lo in-registers (loaded ONCE),
//    double-buffered LDS, one barrier/iter. convA kernels deleted.
//  - sampler v3: bank-conflict-free s_i/s_w (stride-72 h-blocks),
//    saddr-form gathers (32-bit byte offsets), writes pre as f32.
// Split trick: C = Ahi*Bhi + Alo*Bhi + Ahi*Blo (f16 MFMA, f32 acc)
//   B'' [N,768] f16 = [Bhi ; Bhi ; Blo] k-blocks (k contiguous per n)
// Shapes fixed: M=Lq=L_in=21760, C=256, NH=8, NL=4, NP=4,
// levels (128,128)(64,64)(32,32)(16,16), lsi {0,16384,20480,21504}
// ---------------------------------------------------------------------------

typedef _Float16 f16;
typedef _Float16 f16x8 __attribute__((ext_vector_type(8)));
typedef float    f32x4 __attribute__((ext_vector_type(4)));

__device__ __forceinline__ void g2lds16(const void* gp, void* lp) {
    __builtin_amdgcn_global_load_lds(
        (const __attribute__((address_space(1))) unsigned int*)gp,
        (__attribute__((address_space(3))) unsigned int*)lp, 16, 0, 0);
}

// ---- split-f16 MFMA GEMM, A in f32: C[M,N] = split(A[M,256]) x B''[N,768]^T + bias
// 64x128 tile, 512 thr (8 waves 2x4, wave-tile 32x32), BK=64, XOR-swizzled LDS,
// LDS double-buffered; A cached in 32 regs/thread (loaded once).
template <bool HALF_OUT, bool MASKED>
__global__ __launch_bounds__(512) void gemm_f32a(
    const float* __restrict__ Af,   // [M,256] f32
    const f16* __restrict__ Bt,     // [N,768] f16 (k contiguous per n)
    const float* __restrict__ bias, // [N]
    void* __restrict__ Cout, int M, int N,
    const unsigned char* __restrict__ mask)
{
    __shared__ __align__(16) f16 As[2][64 * 64];    // 2 x 8 KB
    __shared__ __align__(16) f16 Bs[2][128 * 64];   // 2 x 16 KB

    const int tid  = threadIdx.x;
    const int m0   = blockIdx.y * 64, n0 = blockIdx.x * 128;
    const int lane = tid & 63, wid = tid >> 6;
    const int wm   = (wid >> 2) * 32, wn = (wid & 3) * 32;

    // ---- A reg cache: thread owns row (tid>>3), f32 cols g*64 + (tid&7)*8 .. +7
    const int arow = tid >> 3;     // 0..63
    const int acb  = tid & 7;      // 0..7
    float4 ar[4][2];
#pragma unroll
    for (int g = 0; g < 4; ++g)
#pragma unroll
        for (int h2 = 0; h2 < 2; ++h2)
            ar[g][h2] = *reinterpret_cast<const float4*>(
                Af + (size_t)(m0 + arow) * 256 + g * 64 + acb * 8 + h2 * 4);

    f32x4 acc[2][2] = {};

    // A stage from regs: kt -> (g, lo?) ; write swizzled f16x8
    auto stageA = [&](int buf, int kt) {
        const int  g  = kt < 4 ? kt : (kt < 8 ? kt - 4 : kt - 8);
        const bool lo = (kt >= 4 && kt < 8);
        f16x8 v;
#pragma unroll
        for (int h2 = 0; h2 < 2; ++h2) {
            const float4 f = ar[g][h2];
            const float fv[4] = {f.x, f.y, f.z, f.w};
#pragma unroll
            for (int j = 0; j < 4; ++j) {
                const f16 hi = (f16)fv[j];
                v[h2 * 4 + j] = lo ? (f16)(fv[j] - (float)hi) : hi;
            }
        }
        const int cc = acb ^ (arow & 7);
        *reinterpret_cast<f16x8*>(&As[buf][arow * 64 + cc * 8]) = v;
    };
    // B stage via global_load_lds (linear dest, pre-swizzled source)
    const int sr  = tid >> 3;
    const int sch = tid & 7;
    auto stageB = [&](int buf, int kt) {
#pragma unroll
        for (int p = 0; p < 2; ++p) {
            const int r  = p * 64 + sr;
            const int gc = (sch ^ (r & 7)) << 3;
            g2lds16(Bt + (size_t)(n0 + r) * 768 + kt * 64 + gc,
                    &Bs[buf][r * 64 + sch * 8]);
        }
    };

    stageB(0, 0);
    stageA(0, 0);

#pragma unroll
    for (int kt = 0; kt < 12; ++kt) {
        const int cur = kt & 1;
        __syncthreads();   // stage(kt) complete (vmcnt0+lgkm0 before barrier)

        // fragment reads first...
        f16x8 av[2][2], bv[2][2];
#pragma unroll
        for (int kf = 0; kf < 2; ++kf) {
            const int kch = kf * 4 + (lane >> 4);
#pragma unroll
            for (int mf = 0; mf < 2; ++mf) {
                const int row = wm + mf * 16 + (lane & 15);
                av[kf][mf] = *(const f16x8*)&As[cur][row * 64 + ((kch ^ (row & 7)) << 3)];
            }
#pragma unroll
            for (int nf = 0; nf < 2; ++nf) {
                const int row = wn + nf * 16 + (lane & 15);
                bv[kf][nf] = *(const f16x8*)&Bs[cur][row * 64 + ((kch ^ (row & 7)) << 3)];
            }
        }
        // ...then issue next-tile staging (overlaps with MFMA below)...
        if (kt < 11) { stageB(cur ^ 1, kt + 1); stageA(cur ^ 1, kt + 1); }
        // ...then MFMA
#pragma unroll
        for (int kf = 0; kf < 2; ++kf)
#pragma unroll
            for (int mf = 0; mf < 2; ++mf)
#pragma unroll
                for (int nf = 0; nf < 2; ++nf)
                    acc[mf][nf] = __builtin_amdgcn_mfma_f32_16x16x32_f16(
                        av[kf][mf], bv[kf][nf], acc[mf][nf], 0, 0, 0);
    }

    // epilogue — C/D layout: col = lane&15, row = (lane>>4)*4 + reg  [m89]
#pragma unroll
    for (int mf = 0; mf < 2; ++mf) {
        const int rb = m0 + wm + mf * 16 + ((lane >> 4) << 2);
#pragma unroll
        for (int nf = 0; nf < 2; ++nf) {
            const int col = n0 + wn + nf * 16 + (lane & 15);
            const float bc = bias[col];
#pragma unroll
            for (int j = 0; j < 4; ++j) {
                const int row = rb + j;
                float v = acc[mf][nf][j] + bc;
                if (MASKED) v = mask[row] ? 0.f : v;
                if (HALF_OUT)
                    ((__half*)Cout)[(size_t)row * N + col] = __float2half(v);
                else
                    ((float*)Cout)[(size_t)row * N + col] = v;
            }
        }
    }
}

// ---- fused weight prep: Btv | Btoa(off+attn) | Btout | boa
__global__ __launch_bounds__(256) void prep_kernel(
    const float* __restrict__ Wv,   const float* __restrict__ Woff,
    const float* __restrict__ Wattn,const float* __restrict__ Wout,
    const float* __restrict__ boff, const float* __restrict__ battn,
    f16* __restrict__ Btv, f16* __restrict__ Btoa, f16* __restrict__ Btout,
    float* __restrict__ boa)
{
    const int i = blockIdx.x * 256 + threadIdx.x;
    constexpr int S0 = 256 * 768, S1 = 256 * 768, S2 = 128 * 768, S3 = 256 * 768;
    if (i < S0) {
        const int n = i / 768, k = i - n * 768, ks = k & 255;
        const float w = Wv[(size_t)ks * 256 + n];
        const f16 h = (f16)w;
        Btv[i] = (k < 512) ? h : (f16)(w - (float)h);
    } else if (i < S0 + S1) {
        const int j = i - S0;
        const int n = j / 768, k = j - n * 768, ks = k & 255;
        const float w = Woff[(size_t)ks * 256 + n];
        const f16 h = (f16)w;
        Btoa[j] = (k < 512) ? h : (f16)(w - (float)h);
    } else if (i < S0 + S1 + S2) {
        const int j = i - S0 - S1;
        const int n = j / 768, k = j - n * 768, ks = k & 255;
        const float w = Wattn[(size_t)ks * 128 + n];
        const f16 h = (f16)w;
        Btoa[(size_t)(256 + n) * 768 + k] = (k < 512) ? h : (f16)(w - (float)h);
    } else if (i < S0 + S1 + S2 + S3) {
        const int j = i - S0 - S1 - S2;
        const int n = j / 768, k = j - n * 768, ks = k & 255;
        const float w = Wout[(size_t)ks * 256 + n];
        const f16 h = (f16)w;
        Btout[j] = (k < 512) ? h : (f16)(w - (float)h);
    } else if (i < S0 + S1 + S2 + S3 + 384) {
        const int j = i - S0 - S1 - S2 - S3;
        boa[j] = (j < 256) ? boff[j] : battn[j - 256];
    }
}

// ---- sampler v3: 2 queries/block; stride-72 h-blocks in s_i/s_w (bank-free);
//      saddr gathers; writes pre as f32 [M,256]
__global__ __launch_bounds__(256) void msda_sample_v3(
    const __half* __restrict__ value,    // [L,256] f16
    const float* __restrict__ offattn,   // [M,384]: off(256) | attn logits(128)
    const float* __restrict__ refp,      // [M,4,2]
    float* __restrict__ pre)             // [M,256] f32
{
    __shared__ float s_off[2][256];
    __shared__ float s_ref[2][8];
    __shared__ __align__(16) float s_w[2][576];   // 8 h-blocks x 72 words
    __shared__ __align__(16) int   s_i[2][576];   // byte offsets of corner rows

    const int q0 = blockIdx.x * 2, tid = threadIdx.x;
#pragma unroll
    for (int j = 0; j < 2; ++j) {
        const int idx = tid + j * 256;
        const int ql = idx >> 8, col = idx & 255;
        s_off[ql][col] = offattn[(size_t)(q0 + ql) * 384 + col];
    }
    if (tid < 16) s_ref[tid >> 3][tid & 7] = refp[(size_t)(q0 + (tid >> 3)) * 8 + (tid & 7)];
    __syncthreads();

    // phase 1: thread -> (query, head, point): softmax + coords + weights
    {
        const int ql = tid >> 7, slot = tid & 127;
        const int h = slot >> 4, pp = slot & 15, l = pp >> 2, p = pp & 3;
        float v = offattn[(size_t)(q0 + ql) * 384 + 256 + slot];   // logit
        float mx = v;
#pragma unroll
        for (int o = 1; o < 16; o <<= 1) mx = fmaxf(mx, __shfl_xor(mx, o, 16));
        const float e = expf(v - mx);
        float s = e;
#pragma unroll
        for (int o = 1; o < 16; o <<= 1) s += __shfl_xor(s, o, 16);
        const float a = e / s;

        const int HW_[4]  = {128, 64, 32, 16};
        const int LSI_[4] = {0, 16384, 20480, 21504};
        const int   Wi = HW_[l];
        const float Wf = (float)Wi;
        const float rx = s_ref[ql][l * 2 + 0], ry = s_ref[ql][l * 2 + 1];
        const float ox = s_off[ql][h * 32 + l * 8 + p * 2 + 0];
        const float oy = s_off[ql][h * 32 + l * 8 + p * 2 + 1];
        const float x = (rx + ox / Wf) * Wf - 0.5f;
        const float y = (ry + oy / Wf) * Wf - 0.5f;
        const float x0f = floorf(x), y0f = floorf(y);
        const float dx = x - x0f, dy = y - y0f;
        const int x0 = (int)x0f, y0 = (int)y0f;
        const int x1 = x0 + 1, y1 = y0 + 1;
        const float vx0 = (x0 >= 0 && x0 < Wi) ? 1.f : 0.f;
        const float vx1 = (x1 >= 0 && x1 < Wi) ? 1.f : 0.f;
        const float vy0 = (y0 >= 0 && y0 < Wi) ? 1.f : 0.f;
        const float vy1 = (y1 >= 0 && y1 < Wi) ? 1.f : 0.f;
        const int xc0 = min(max(x0, 0), Wi - 1), xc1 = min(max(x1, 0), Wi - 1);
        const int yc0 = min(max(y0, 0), Wi - 1), yc1 = min(max(y1, 0), Wi - 1);
        const int base = LSI_[l];
        const int eI = h * 72 + pp * 4;           // stride-72 h-blocks
        s_i[ql][eI + 0] = (base + yc0 * Wi + xc0) * 512;   // row byte offsets
        s_i[ql][eI + 1] = (base + yc0 * Wi + xc1) * 512;
        s_i[ql][eI + 2] = (base + yc1 * Wi + xc0) * 512;
        s_i[ql][eI + 3] = (base + yc1 * Wi + xc1) * 512;
        s_w[ql][eI + 0] = a * (1.f - dy) * (1.f - dx) * vy0 * vx0;
        s_w[ql][eI + 1] = a * (1.f - dy) * dx         * vy0 * vx1;
        s_w[ql][eI + 2] = a * dy         * (1.f - dx) * vy1 * vx0;
        s_w[ql][eI + 3] = a * dy         * dx         * vy1 * vx1;
    }
    __syncthreads();

    // phase 2: thread=(ql, h, cp): saddr half2 gathers + fma_mix accumulate
    const int ql = tid >> 7, slot = tid & 127;
    const int h = slot >> 4, cp = slot & 15;
    const int lb = h * 64 + cp * 4;               // lane byte offset within row
    const char* __restrict__ vbase = (const char*)value;
    float acc0 = 0.f, acc1 = 0.f;
#pragma unroll
    for (int pp = 0; pp < 16; ++pp) {
        const int eI = h * 72 + pp * 4;
        const int4   idx = *reinterpret_cast<const int4*>(&s_i[ql][eI]);
        const float4 w   = *reinterpret_cast<const float4*>(&s_w[ql][eI]);
        const __half2 v0 = *reinterpret_cast<const __half2*>(vbase + (idx.x + lb));
        const __half2 v1 = *reinterpret_cast<const __half2*>(vbase + (idx.y + lb));
        const __half2 v2 = *reinterpret_cast<const __half2*>(vbase + (idx.z + lb));
        const __half2 v3 = *reinterpret_cast<const __half2*>(vbase + (idx.w + lb));
        acc0 = fmaf(w.x, __half2float(v0.x), acc0);
        acc1 = fmaf(w.x, __half2float(v0.y), acc1);
        acc0 = fmaf(w.y, __half2float(v1.x), acc0);
        acc1 = fmaf(w.y, __half2float(v1.y), acc1);
        acc0 = fmaf(w.z, __half2float(v2.x), acc0);
        acc1 = fmaf(w.z, __half2float(v2.y), acc1);
        acc0 = fmaf(w.w, __half2float(v3.x), acc0);
        acc1 = fmaf(w.w, __half2float(v3.y), acc1);
    }
    float2 o; o.x = acc0; o.y = acc1;
    *reinterpret_cast<float2*>(&pre[(size_t)(q0 + ql) * 256 + h * 32 + cp * 2]) = o;
}

extern "C" void kernel_launch(void* const* d_in, const int* in_sizes, int n_in,
                              void* d_out, int out_size, void* d_ws, size_t ws_size,
                              hipStream_t stream)
{
    const float*         query  = (const float*)d_in[0];
    const float*         refp   = (const float*)d_in[1];
    const float*         inF    = (const float*)d_in[2];
    const unsigned char* mask   = (const unsigned char*)d_in[5];
    const float*         W_off  = (const float*)d_in[6];
    const float*         b_off  = (const float*)d_in[7];
    const float*         W_attn = (const float*)d_in[8];
    const float*         b_attn = (const float*)d_in[9];
    const float*         W_v    = (const float*)d_in[10];
    const float*         b_v    = (const float*)d_in[11];
    const float*         W_out  = (const float*)d_in[12];
    const float*         b_out  = (const float*)d_in[13];
    float*               out    = (float*)d_out;

    const int M = in_sizes[0] / 256;          // 21760
    if (M % 128 != 0) return;                 // tiling/pairing guard

    const size_t SZ_VAL = (size_t)M * 256 * sizeof(__half);   // 11.1 MB
    const size_t SZ_OA  = (size_t)M * 384 * sizeof(float);    // 33.4 MB
    const size_t SZ_PRE = (size_t)M * 256 * sizeof(float);    // 22.3 MB
    const size_t SZ_BTV = 256 * 768 * sizeof(f16);
    const size_t SZ_BTO = 384 * 768 * sizeof(f16);
    char* w = (char*)d_ws;
    __half* valueH = (__half*)w;                   w += SZ_VAL;
    float*  offattn= (float*)w;                    w += SZ_OA;
    float*  pre    = (float*)w;                    w += SZ_PRE;
    f16*    Btv    = (f16*)w;                      w += SZ_BTV;
    f16*    Btoa   = (f16*)w;                      w += SZ_BTO;
    f16*    Btout  = (f16*)w;                      w += SZ_BTV;
    float*  boa    = (float*)w;                    w += 512 * sizeof(float);
    if ((size_t)(w - (char*)d_ws) > ws_size) return;  // clean fail, no OOB

    const dim3 blk256(256), blk512(512);
    const int prep_total = 3 * 256 * 768 + 128 * 768 + 384;

    prep_kernel<<<dim3((prep_total + 255) / 256), blk256, 0, stream>>>(
        W_v, W_off, W_attn, W_out, b_off, b_attn, Btv, Btoa, Btout, boa);

    // value = inF @ W_v + b_v (masked) -> f16
    gemm_f32a<true, true><<<dim3(2, M / 64), blk512, 0, stream>>>(
        inF, Btv, b_v, valueH, M, 256, mask);

    // [off | attn logits] = query @ [W_off|W_attn] + [b_off|b_attn]
    gemm_f32a<false, false><<<dim3(3, M / 64), blk512, 0, stream>>>(
        query, Btoa, boa, offattn, M, 384, nullptr);

    // sampling (+softmax) -> pre f32
    msda_sample_v3<<<dim3(M / 2), blk256, 0, stream>>>(valueH, offattn, refp, pre);

    // out = pre @ W_out + b_out
    gemm_f32a<false, false><<<dim3(2, M / 64), blk512, 0, stream>>>(
        pre, Btout, b_out, out, M, 256, nullptr);
}